// Round 5
// baseline (468.098 us; speedup 1.0000x reference)
//
#include <hip/hip_runtime.h>
#include <math.h>

// ATTRIBUTION ROUND: byte-exact R1 kernels (best known, 142.5 us), but k1 is
// launched 17x (idempotent). dur_us = base + 16*(T_k1 + gap) resolves where
// the time goes. Recover best-known by dropping the loop.

// Problem constants (from setup_inputs): H=1024, B=32, S=4096, all f32.
constexpr int H = 1024;
constexpr int B = 32;
constexpr int S = 4096;
constexpr int STILE = 64;   // s-rows per block in energies kernel

// ---------------------------------------------------------------------------
// Kernel 1: v[b,h] = sum_g hidden[b,g] * W[g,h]   (R1 version: scalar W loads)
// ---------------------------------------------------------------------------
__global__ __launch_bounds__(256) void compute_v_kernel(
    const float* __restrict__ hidden, const float* __restrict__ W,
    float* __restrict__ v)
{
    const int h = ((blockIdx.x & 3) << 8) + threadIdx.x;
    const int b = blockIdx.x >> 2;
    const float* __restrict__ hb = hidden + b * H;
    float a0 = 0.f, a1 = 0.f, a2 = 0.f, a3 = 0.f;
    for (int g = 0; g < H; g += 4) {
        a0 = fmaf(hb[g + 0], W[(g + 0) * H + h], a0);
        a1 = fmaf(hb[g + 1], W[(g + 1) * H + h], a1);
        a2 = fmaf(hb[g + 2], W[(g + 2) * H + h], a2);
        a3 = fmaf(hb[g + 3], W[(g + 3) * H + h], a3);
    }
    v[b * H + h] = (a0 + a1) + (a2 + a3);
}

// ---------------------------------------------------------------------------
// Kernel 2: energies[b,s] = v[b,:] . enc[s,b,:]   (R1 version: LDS v, 1 row
// per wave-iteration)
// ---------------------------------------------------------------------------
__global__ __launch_bounds__(256) void energies_kernel(
    const float* __restrict__ enc, const float* __restrict__ v,
    float* __restrict__ energies)
{
    constexpr int tilesPerB = S / STILE;              // 64
    const int b  = blockIdx.x / tilesPerB;
    const int s0 = (blockIdx.x % tilesPerB) * STILE;

    __shared__ float4 vs[H / 4];
    const float4* __restrict__ vb = (const float4*)(v + b * H);
    for (int i = threadIdx.x; i < H / 4; i += 256) vs[i] = vb[i];
    __syncthreads();

    const int wave = threadIdx.x >> 6;
    const int lane = threadIdx.x & 63;

    for (int si = wave; si < STILE; si += 4) {
        const int s = s0 + si;
        const float4* __restrict__ row =
            (const float4*)(enc + ((size_t)s * B + b) * H);
        float acc = 0.f;
        #pragma unroll
        for (int it = 0; it < 4; ++it) {
            float4 e = row[it * 64 + lane];
            float4 w = vs[it * 64 + lane];
            acc = fmaf(e.x, w.x, acc);
            acc = fmaf(e.y, w.y, acc);
            acc = fmaf(e.z, w.z, acc);
            acc = fmaf(e.w, w.w, acc);
        }
        #pragma unroll
        for (int off = 32; off > 0; off >>= 1)
            acc += __shfl_xor(acc, off, 64);
        if (lane == 0) energies[b * S + s] = acc;
    }
}

// ---------------------------------------------------------------------------
// Kernel 3: in-place row softmax over d_out[b, 0, :]   (R1 version: scalar)
// ---------------------------------------------------------------------------
__global__ __launch_bounds__(256) void softmax_kernel(float* __restrict__ out)
{
    const int b = blockIdx.x;
    float* __restrict__ row = out + (size_t)b * S;
    __shared__ float redm[4];
    __shared__ float reds[4];
    const int wave = threadIdx.x >> 6;
    const int lane = threadIdx.x & 63;

    float vals[S / 256];                 // 16 registers
    float m = -INFINITY;
    #pragma unroll
    for (int k = 0; k < S / 256; ++k) {
        vals[k] = row[threadIdx.x + k * 256];
        m = fmaxf(m, vals[k]);
    }
    #pragma unroll
    for (int off = 32; off > 0; off >>= 1)
        m = fmaxf(m, __shfl_xor(m, off, 64));
    if (lane == 0) redm[wave] = m;
    __syncthreads();
    m = fmaxf(fmaxf(redm[0], redm[1]), fmaxf(redm[2], redm[3]));

    float ssum = 0.f;
    #pragma unroll
    for (int k = 0; k < S / 256; ++k) {
        vals[k] = __expf(vals[k] - m);
        ssum += vals[k];
    }
    #pragma unroll
    for (int off = 32; off > 0; off >>= 1)
        ssum += __shfl_xor(ssum, off, 64);
    if (lane == 0) reds[wave] = ssum;
    __syncthreads();
    const float inv = 1.0f / ((reds[0] + reds[1]) + (reds[2] + reds[3]));
    #pragma unroll
    for (int k = 0; k < S / 256; ++k)
        row[threadIdx.x + k * 256] = vals[k] * inv;
}

extern "C" void kernel_launch(void* const* d_in, const int* in_sizes, int n_in,
                              void* d_out, int out_size, void* d_ws, size_t ws_size,
                              hipStream_t stream) {
    const float* hidden = (const float*)d_in[0];   // [1, B, H]
    const float* enc    = (const float*)d_in[1];   // [S, B, H]
    const float* W      = (const float*)d_in[2];   // [H, H]
    // d_in[3] = attn_b: per-b constant in energies -> cancels under softmax.
    float* out = (float*)d_out;                    // [B, 1, S]
    float* v   = (float*)d_ws;                     // B*H floats

    // 17x launch: idempotent, measures T_k1 via dur_us = base + 16*(T_k1+gap)
    for (int rep = 0; rep < 17; ++rep)
        compute_v_kernel<<<dim3(B * 4), dim3(256), 0, stream>>>(hidden, W, v);
    energies_kernel<<<dim3(B * (S / STILE)), dim3(256), 0, stream>>>(enc, v, out);
    softmax_kernel<<<dim3(B), dim3(256), 0, stream>>>(out);
}

// Round 6
// 131.529 us; speedup vs baseline: 3.5589x; 3.5589x over previous
//
#include <hip/hip_runtime.h>
#include <math.h>

// Problem constants (from setup_inputs): H=1024, B=32, S=4096, all f32.
constexpr int H = 1024;
constexpr int B = 32;
constexpr int S = 4096;
constexpr int STILE = 64;   // s-rows per block in energies kernel

// ---------------------------------------------------------------------------
// Kernel 1 v3: v[b,h] = sum_g hidden[b,g] * W[g,h]
// R5 measured v1 at ~20 us (latency-bound: 128 blocks, scalar loads).
// v3: 512 blocks = b x 16 h-chunks(64 wide); 256 thr = 16 h-quads x 16-way
// g-split (64 g/thread); float4 W loads, unroll 4 -> 8 float4 in flight
// (~32 VGPR, no spill — R2's unroll-8/16-float4 version spilled).
// Two-stage LDS combine. Predicted ~4 us (128 MiB L2 traffic).
// ---------------------------------------------------------------------------
__global__ __launch_bounds__(256) void compute_v_kernel(
    const float* __restrict__ hidden, const float* __restrict__ W,
    float* __restrict__ v)
{
    const int b  = blockIdx.x >> 4;
    const int hc = blockIdx.x & 15;           // 64-wide h chunk
    const int hq = threadIdx.x & 15;          // h-quad within chunk
    const int gg = threadIdx.x >> 4;          // 16-way g-split
    const int hquad = hc * 16 + hq;           // global h/4 index
    const float* __restrict__ hb = hidden + b * H;
    const float4* __restrict__ W4 = (const float4*)W;   // W4[g*256 + h/4]

    float4 aE = {0,0,0,0}, aO = {0,0,0,0};
    const int g0 = gg * 64;
    #pragma unroll 4
    for (int g = g0; g < g0 + 64; g += 2) {
        float  h0 = hb[g], h1 = hb[g + 1];
        float4 w0 = W4[(size_t)(g + 0) * 256 + hquad];
        float4 w1 = W4[(size_t)(g + 1) * 256 + hquad];
        aE.x = fmaf(h0, w0.x, aE.x); aE.y = fmaf(h0, w0.y, aE.y);
        aE.z = fmaf(h0, w0.z, aE.z); aE.w = fmaf(h0, w0.w, aE.w);
        aO.x = fmaf(h1, w1.x, aO.x); aO.y = fmaf(h1, w1.y, aO.y);
        aO.z = fmaf(h1, w1.z, aO.z); aO.w = fmaf(h1, w1.w, aO.w);
    }
    float4 acc = {aE.x + aO.x, aE.y + aO.y, aE.z + aO.z, aE.w + aO.w};

    __shared__ float4 part[16][16];
    part[gg][hq] = acc;
    __syncthreads();
    if (threadIdx.x < 64) {                   // stage 1: 16 -> 4 partials
        const int q  = threadIdx.x & 15;
        const int kk = threadIdx.x >> 4;
        float4 s = part[kk * 4 + 0][q];
        #pragma unroll
        for (int j = 1; j < 4; ++j) {
            float4 p = part[kk * 4 + j][q];
            s.x += p.x; s.y += p.y; s.z += p.z; s.w += p.w;
        }
        part[kk * 4][q] = s;
    }
    __syncthreads();
    if (threadIdx.x < 16) {                   // stage 2: 4 -> 1, store
        const int q = threadIdx.x;
        float4 s = part[0][q];
        #pragma unroll
        for (int j = 1; j < 4; ++j) {
            float4 p = part[j * 4][q];
            s.x += p.x; s.y += p.y; s.z += p.z; s.w += p.w;
        }
        ((float4*)(v + b * H))[hquad] = s;
    }
}

// ---------------------------------------------------------------------------
// Kernel 2: energies[b,s] = v[b,:] . enc[s,b,:]  — byte-identical to R1's k2
// EXCEPT the block-index mapping: b is now the FAST dimension, so the
// resident block cohort spans all 32 b's (full 128 KiB address window /
// all HBM channels) instead of hammering a few b columns at 128 KiB stride.
// ---------------------------------------------------------------------------
__global__ __launch_bounds__(256) void energies_kernel(
    const float* __restrict__ enc, const float* __restrict__ v,
    float* __restrict__ energies)
{
    const int b  = blockIdx.x & 31;                   // FAST dim (was /64)
    const int s0 = (blockIdx.x >> 5) * STILE;

    __shared__ float4 vs[H / 4];
    const float4* __restrict__ vb = (const float4*)(v + b * H);
    for (int i = threadIdx.x; i < H / 4; i += 256) vs[i] = vb[i];
    __syncthreads();

    const int wave = threadIdx.x >> 6;
    const int lane = threadIdx.x & 63;

    for (int si = wave; si < STILE; si += 4) {
        const int s = s0 + si;
        const float4* __restrict__ row =
            (const float4*)(enc + ((size_t)s * B + b) * H);
        float acc = 0.f;
        #pragma unroll
        for (int it = 0; it < 4; ++it) {
            float4 e = row[it * 64 + lane];
            float4 w = vs[it * 64 + lane];
            acc = fmaf(e.x, w.x, acc);
            acc = fmaf(e.y, w.y, acc);
            acc = fmaf(e.z, w.z, acc);
            acc = fmaf(e.w, w.w, acc);
        }
        #pragma unroll
        for (int off = 32; off > 0; off >>= 1)
            acc += __shfl_xor(acc, off, 64);
        if (lane == 0) energies[b * S + s] = acc;
    }
}

// ---------------------------------------------------------------------------
// Kernel 3: in-place row softmax over d_out[b, 0, :]   (R1 version)
// ---------------------------------------------------------------------------
__global__ __launch_bounds__(256) void softmax_kernel(float* __restrict__ out)
{
    const int b = blockIdx.x;
    float* __restrict__ row = out + (size_t)b * S;
    __shared__ float redm[4];
    __shared__ float reds[4];
    const int wave = threadIdx.x >> 6;
    const int lane = threadIdx.x & 63;

    float vals[S / 256];                 // 16 registers
    float m = -INFINITY;
    #pragma unroll
    for (int k = 0; k < S / 256; ++k) {
        vals[k] = row[threadIdx.x + k * 256];
        m = fmaxf(m, vals[k]);
    }
    #pragma unroll
    for (int off = 32; off > 0; off >>= 1)
        m = fmaxf(m, __shfl_xor(m, off, 64));
    if (lane == 0) redm[wave] = m;
    __syncthreads();
    m = fmaxf(fmaxf(redm[0], redm[1]), fmaxf(redm[2], redm[3]));

    float ssum = 0.f;
    #pragma unroll
    for (int k = 0; k < S / 256; ++k) {
        vals[k] = __expf(vals[k] - m);
        ssum += vals[k];
    }
    #pragma unroll
    for (int off = 32; off > 0; off >>= 1)
        ssum += __shfl_xor(ssum, off, 64);
    if (lane == 0) reds[wave] = ssum;
    __syncthreads();
    const float inv = 1.0f / ((reds[0] + reds[1]) + (reds[2] + reds[3]));
    #pragma unroll
    for (int k = 0; k < S / 256; ++k)
        row[threadIdx.x + k * 256] = vals[k] * inv;
}

extern "C" void kernel_launch(void* const* d_in, const int* in_sizes, int n_in,
                              void* d_out, int out_size, void* d_ws, size_t ws_size,
                              hipStream_t stream) {
    const float* hidden = (const float*)d_in[0];   // [1, B, H]
    const float* enc    = (const float*)d_in[1];   // [S, B, H]
    const float* W      = (const float*)d_in[2];   // [H, H]
    // d_in[3] = attn_b: per-b constant in energies -> cancels under softmax.
    float* out = (float*)d_out;                    // [B, 1, S]
    float* v   = (float*)d_ws;                     // B*H floats

    compute_v_kernel<<<dim3(B * 16), dim3(256), 0, stream>>>(hidden, W, v);
    energies_kernel<<<dim3(B * (S / STILE)), dim3(256), 0, stream>>>(enc, v, out);
    softmax_kernel<<<dim3(B), dim3(256), 0, stream>>>(out);
}

// Round 7
// 112.190 us; speedup vs baseline: 4.1724x; 1.1724x over previous
//
#include <hip/hip_runtime.h>
#include <math.h>

// Problem constants (from setup_inputs): H=1024, B=32, S=4096, all f32.
constexpr int H = 1024;
constexpr int B = 32;
constexpr int S = 4096;

// ---------------------------------------------------------------------------
// Kernel 1 v3 (unchanged from R6): v[b,h] = sum_g hidden[b,g] * W[g,h]
// ---------------------------------------------------------------------------
__global__ __launch_bounds__(256) void compute_v_kernel(
    const float* __restrict__ hidden, const float* __restrict__ W,
    float* __restrict__ v)
{
    const int b  = blockIdx.x >> 4;
    const int hc = blockIdx.x & 15;           // 64-wide h chunk
    const int hq = threadIdx.x & 15;          // h-quad within chunk
    const int gg = threadIdx.x >> 4;          // 16-way g-split
    const int hquad = hc * 16 + hq;           // global h/4 index
    const float* __restrict__ hb = hidden + b * H;
    const float4* __restrict__ W4 = (const float4*)W;   // W4[g*256 + h/4]

    float4 aE = {0,0,0,0}, aO = {0,0,0,0};
    const int g0 = gg * 64;
    #pragma unroll 4
    for (int g = g0; g < g0 + 64; g += 2) {
        float  h0 = hb[g], h1 = hb[g + 1];
        float4 w0 = W4[(size_t)(g + 0) * 256 + hquad];
        float4 w1 = W4[(size_t)(g + 1) * 256 + hquad];
        aE.x = fmaf(h0, w0.x, aE.x); aE.y = fmaf(h0, w0.y, aE.y);
        aE.z = fmaf(h0, w0.z, aE.z); aE.w = fmaf(h0, w0.w, aE.w);
        aO.x = fmaf(h1, w1.x, aO.x); aO.y = fmaf(h1, w1.y, aO.y);
        aO.z = fmaf(h1, w1.z, aO.z); aO.w = fmaf(h1, w1.w, aO.w);
    }
    float4 acc = {aE.x + aO.x, aE.y + aO.y, aE.z + aO.z, aE.w + aO.w};

    __shared__ float4 part[16][16];
    part[gg][hq] = acc;
    __syncthreads();
    if (threadIdx.x < 64) {                   // stage 1: 16 -> 4 partials
        const int q  = threadIdx.x & 15;
        const int kk = threadIdx.x >> 4;
        float4 s = part[kk * 4 + 0][q];
        #pragma unroll
        for (int j = 1; j < 4; ++j) {
            float4 p = part[kk * 4 + j][q];
            s.x += p.x; s.y += p.y; s.z += p.z; s.w += p.w;
        }
        part[kk * 4][q] = s;
    }
    __syncthreads();
    if (threadIdx.x < 16) {                   // stage 2: 4 -> 1, store
        const int q = threadIdx.x;
        float4 s = part[0][q];
        #pragma unroll
        for (int j = 1; j < 4; ++j) {
            float4 p = part[j * 4][q];
            s.x += p.x; s.y += p.y; s.z += p.z; s.w += p.w;
        }
        ((float4*)(v + b * H))[hquad] = s;
    }
}

// ---------------------------------------------------------------------------
// Kernel 2 v4: CONTIGUOUS-SWEEP energies.
// Block = 1024 thr (16 waves), grid = 256 blocks (1/CU). Block sweeps rows
// r in [blockIdx*512, blockIdx*512+512) of enc's natural [S*B] row order —
// a fully contiguous 2 MiB span. Per k-step the 16 waves read 32 consecutive
// rows (128 KiB contiguous). Wave w's rows have b = r&31 in {w, w+16} only,
// so its two v-fragments live in 8 float4 registers — no LDS staging.
// Tests the DRAM-page-locality hypothesis for the 68%-of-peak plateau.
// ---------------------------------------------------------------------------
__global__ __launch_bounds__(1024) void energies_kernel(
    const float* __restrict__ enc, const float* __restrict__ v,
    float* __restrict__ energies)
{
    const int w    = threadIdx.x >> 6;        // wave 0..15
    const int lane = threadIdx.x & 63;
    const int b0 = w, b1 = w + 16;
    const size_t base   = (size_t)blockIdx.x * 512;   // first row r of block
    const int    s_base = blockIdx.x * 16;

    const float4* __restrict__ v4 = (const float4*)v;
    const float4 wa0 = v4[b0 * 256 + lane],       wa1 = v4[b0 * 256 + 64 + lane],
                 wa2 = v4[b0 * 256 + 128 + lane], wa3 = v4[b0 * 256 + 192 + lane];
    const float4 wb0 = v4[b1 * 256 + lane],       wb1 = v4[b1 * 256 + 64 + lane],
                 wb2 = v4[b1 * 256 + 128 + lane], wb3 = v4[b1 * 256 + 192 + lane];

    for (int k = 0; k < 16; ++k) {
        // row A: r = base + w + 32k  -> (s_base+k, b0)
        // row B: r = base + w + 32k + 16 -> (s_base+k, b1)
        const float4* __restrict__ rowA =
            (const float4*)enc + (base + (size_t)w + 32u * k) * 256;
        const float4* __restrict__ rowB = rowA + 16 * 256;
        float4 a0 = rowA[lane],       a1 = rowA[64 + lane],
               a2 = rowA[128 + lane], a3 = rowA[192 + lane];
        float4 e0 = rowB[lane],       e1 = rowB[64 + lane],
               e2 = rowB[128 + lane], e3 = rowB[192 + lane];

        float pa0 = a0.x * wa0.x, pa1 = a1.x * wa1.x;
        float pb0 = e0.x * wb0.x, pb1 = e1.x * wb1.x;
        pa0 = fmaf(a0.y, wa0.y, pa0); pa1 = fmaf(a1.y, wa1.y, pa1);
        pb0 = fmaf(e0.y, wb0.y, pb0); pb1 = fmaf(e1.y, wb1.y, pb1);
        pa0 = fmaf(a0.z, wa0.z, pa0); pa1 = fmaf(a1.z, wa1.z, pa1);
        pb0 = fmaf(e0.z, wb0.z, pb0); pb1 = fmaf(e1.z, wb1.z, pb1);
        pa0 = fmaf(a0.w, wa0.w, pa0); pa1 = fmaf(a1.w, wa1.w, pa1);
        pb0 = fmaf(e0.w, wb0.w, pb0); pb1 = fmaf(e1.w, wb1.w, pb1);
        pa0 = fmaf(a2.x, wa2.x, pa0); pa1 = fmaf(a3.x, wa3.x, pa1);
        pb0 = fmaf(e2.x, wb2.x, pb0); pb1 = fmaf(e3.x, wb3.x, pb1);
        pa0 = fmaf(a2.y, wa2.y, pa0); pa1 = fmaf(a3.y, wa3.y, pa1);
        pb0 = fmaf(e2.y, wb2.y, pb0); pb1 = fmaf(e3.y, wb3.y, pb1);
        pa0 = fmaf(a2.z, wa2.z, pa0); pa1 = fmaf(a3.z, wa3.z, pa1);
        pb0 = fmaf(e2.z, wb2.z, pb0); pb1 = fmaf(e3.z, wb3.z, pb1);
        pa0 = fmaf(a2.w, wa2.w, pa0); pa1 = fmaf(a3.w, wa3.w, pa1);
        pb0 = fmaf(e2.w, wb2.w, pb0); pb1 = fmaf(e3.w, wb3.w, pb1);
        float pa = pa0 + pa1;
        float pb = pb0 + pb1;

        #pragma unroll
        for (int off = 32; off > 0; off >>= 1) {
            pa += __shfl_xor(pa, off, 64);
            pb += __shfl_xor(pb, off, 64);
        }
        if (lane == 0) {
            energies[(size_t)b0 * S + s_base + k] = pa;
            energies[(size_t)b1 * S + s_base + k] = pb;
        }
    }
}

// ---------------------------------------------------------------------------
// Kernel 3 (unchanged from R6): in-place row softmax over d_out[b, 0, :]
// ---------------------------------------------------------------------------
__global__ __launch_bounds__(256) void softmax_kernel(float* __restrict__ out)
{
    const int b = blockIdx.x;
    float* __restrict__ row = out + (size_t)b * S;
    __shared__ float redm[4];
    __shared__ float reds[4];
    const int wave = threadIdx.x >> 6;
    const int lane = threadIdx.x & 63;

    float vals[S / 256];                 // 16 registers
    float m = -INFINITY;
    #pragma unroll
    for (int k = 0; k < S / 256; ++k) {
        vals[k] = row[threadIdx.x + k * 256];
        m = fmaxf(m, vals[k]);
    }
    #pragma unroll
    for (int off = 32; off > 0; off >>= 1)
        m = fmaxf(m, __shfl_xor(m, off, 64));
    if (lane == 0) redm[wave] = m;
    __syncthreads();
    m = fmaxf(fmaxf(redm[0], redm[1]), fmaxf(redm[2], redm[3]));

    float ssum = 0.f;
    #pragma unroll
    for (int k = 0; k < S / 256; ++k) {
        vals[k] = __expf(vals[k] - m);
        ssum += vals[k];
    }
    #pragma unroll
    for (int off = 32; off > 0; off >>= 1)
        ssum += __shfl_xor(ssum, off, 64);
    if (lane == 0) reds[wave] = ssum;
    __syncthreads();
    const float inv = 1.0f / ((reds[0] + reds[1]) + (reds[2] + reds[3]));
    #pragma unroll
    for (int k = 0; k < S / 256; ++k)
        row[threadIdx.x + k * 256] = vals[k] * inv;
}

extern "C" void kernel_launch(void* const* d_in, const int* in_sizes, int n_in,
                              void* d_out, int out_size, void* d_ws, size_t ws_size,
                              hipStream_t stream) {
    const float* hidden = (const float*)d_in[0];   // [1, B, H]
    const float* enc    = (const float*)d_in[1];   // [S, B, H]
    const float* W      = (const float*)d_in[2];   // [H, H]
    // d_in[3] = attn_b: per-b constant in energies -> cancels under softmax.
    float* out = (float*)d_out;                    // [B, 1, S]
    float* v   = (float*)d_ws;                     // B*H floats

    compute_v_kernel<<<dim3(B * 16), dim3(256), 0, stream>>>(hidden, W, v);
    energies_kernel<<<dim3(256), dim3(1024), 0, stream>>>(enc, v, out);
    softmax_kernel<<<dim3(B), dim3(256), 0, stream>>>(out);
}

// Round 8
// 112.028 us; speedup vs baseline: 4.1784x; 1.0014x over previous
//
#include <hip/hip_runtime.h>
#include <math.h>

// Problem constants (from setup_inputs): H=1024, B=32, S=4096, all f32.
constexpr int H = 1024;
constexpr int B = 32;
constexpr int S = 4096;

// ---------------------------------------------------------------------------
// Kernel 1 v3 (unchanged from R6/R7): v[b,h] = sum_g hidden[b,g] * W[g,h]
// ---------------------------------------------------------------------------
__global__ __launch_bounds__(256) void compute_v_kernel(
    const float* __restrict__ hidden, const float* __restrict__ W,
    float* __restrict__ v)
{
    const int b  = blockIdx.x >> 4;
    const int hc = blockIdx.x & 15;           // 64-wide h chunk
    const int hq = threadIdx.x & 15;          // h-quad within chunk
    const int gg = threadIdx.x >> 4;          // 16-way g-split
    const int hquad = hc * 16 + hq;           // global h/4 index
    const float* __restrict__ hb = hidden + b * H;
    const float4* __restrict__ W4 = (const float4*)W;   // W4[g*256 + h/4]

    float4 aE = {0,0,0,0}, aO = {0,0,0,0};
    const int g0 = gg * 64;
    #pragma unroll 4
    for (int g = g0; g < g0 + 64; g += 2) {
        float  h0 = hb[g], h1 = hb[g + 1];
        float4 w0 = W4[(size_t)(g + 0) * 256 + hquad];
        float4 w1 = W4[(size_t)(g + 1) * 256 + hquad];
        aE.x = fmaf(h0, w0.x, aE.x); aE.y = fmaf(h0, w0.y, aE.y);
        aE.z = fmaf(h0, w0.z, aE.z); aE.w = fmaf(h0, w0.w, aE.w);
        aO.x = fmaf(h1, w1.x, aO.x); aO.y = fmaf(h1, w1.y, aO.y);
        aO.z = fmaf(h1, w1.z, aO.z); aO.w = fmaf(h1, w1.w, aO.w);
    }
    float4 acc = {aE.x + aO.x, aE.y + aO.y, aE.z + aO.z, aE.w + aO.w};

    __shared__ float4 part[16][16];
    part[gg][hq] = acc;
    __syncthreads();
    if (threadIdx.x < 64) {                   // stage 1: 16 -> 4 partials
        const int q  = threadIdx.x & 15;
        const int kk = threadIdx.x >> 4;
        float4 s = part[kk * 4 + 0][q];
        #pragma unroll
        for (int j = 1; j < 4; ++j) {
            float4 p = part[kk * 4 + j][q];
            s.x += p.x; s.y += p.y; s.z += p.z; s.w += p.w;
        }
        part[kk * 4][q] = s;
    }
    __syncthreads();
    if (threadIdx.x < 16) {                   // stage 2: 4 -> 1, store
        const int q = threadIdx.x;
        float4 s = part[0][q];
        #pragma unroll
        for (int j = 1; j < 4; ++j) {
            float4 p = part[j * 4][q];
            s.x += p.x; s.y += p.y; s.z += p.z; s.w += p.w;
        }
        ((float4*)(v + b * H))[hquad] = s;
    }
}

// ---------------------------------------------------------------------------
// Kernel 2 v5: contiguous sweep (R7 structure) + EXPLICIT 1-DEEP PREFETCH.
// Ping-pong register sets X/Y: iter k+1's 8 row-loads are issued before
// iter k's FMA+reduce, so each wave keeps 8 KiB outstanding continuously
// (FMAs depend only on the current set -> hw waits at vmcnt(8), not 0).
// ~110-120 VGPR, within __launch_bounds__(1024)'s 128 cap.
// ---------------------------------------------------------------------------
#define LOAD8(pfx, pA, pB)                                                   \
    pfx##a0 = (pA)[lane];        pfx##a1 = (pA)[64 + lane];                  \
    pfx##a2 = (pA)[128 + lane];  pfx##a3 = (pA)[192 + lane];                 \
    pfx##b0 = (pB)[lane];        pfx##b1 = (pB)[64 + lane];                  \
    pfx##b2 = (pB)[128 + lane];  pfx##b3 = (pB)[192 + lane];

#define COMPUTE_STORE(pfx, kk)                                               \
    {                                                                        \
        float pa0 = pfx##a0.x * wa0.x, pa1 = pfx##a1.x * wa1.x;              \
        float pb0 = pfx##b0.x * wb0.x, pb1 = pfx##b1.x * wb1.x;              \
        pa0 = fmaf(pfx##a0.y, wa0.y, pa0); pa1 = fmaf(pfx##a1.y, wa1.y, pa1);\
        pb0 = fmaf(pfx##b0.y, wb0.y, pb0); pb1 = fmaf(pfx##b1.y, wb1.y, pb1);\
        pa0 = fmaf(pfx##a0.z, wa0.z, pa0); pa1 = fmaf(pfx##a1.z, wa1.z, pa1);\
        pb0 = fmaf(pfx##b0.z, wb0.z, pb0); pb1 = fmaf(pfx##b1.z, wb1.z, pb1);\
        pa0 = fmaf(pfx##a0.w, wa0.w, pa0); pa1 = fmaf(pfx##a1.w, wa1.w, pa1);\
        pb0 = fmaf(pfx##b0.w, wb0.w, pb0); pb1 = fmaf(pfx##b1.w, wb1.w, pb1);\
        pa0 = fmaf(pfx##a2.x, wa2.x, pa0); pa1 = fmaf(pfx##a3.x, wa3.x, pa1);\
        pb0 = fmaf(pfx##b2.x, wb2.x, pb0); pb1 = fmaf(pfx##b3.x, wb3.x, pb1);\
        pa0 = fmaf(pfx##a2.y, wa2.y, pa0); pa1 = fmaf(pfx##a3.y, wa3.y, pa1);\
        pb0 = fmaf(pfx##b2.y, wb2.y, pb0); pb1 = fmaf(pfx##b3.y, wb3.y, pb1);\
        pa0 = fmaf(pfx##a2.z, wa2.z, pa0); pa1 = fmaf(pfx##a3.z, wa3.z, pa1);\
        pb0 = fmaf(pfx##b2.z, wb2.z, pb0); pb1 = fmaf(pfx##b3.z, wb3.z, pb1);\
        pa0 = fmaf(pfx##a2.w, wa2.w, pa0); pa1 = fmaf(pfx##a3.w, wa3.w, pa1);\
        pb0 = fmaf(pfx##b2.w, wb2.w, pb0); pb1 = fmaf(pfx##b3.w, wb3.w, pb1);\
        float pa = pa0 + pa1;                                                \
        float pb = pb0 + pb1;                                                \
        _Pragma("unroll")                                                    \
        for (int off = 32; off > 0; off >>= 1) {                             \
            pa += __shfl_xor(pa, off, 64);                                   \
            pb += __shfl_xor(pb, off, 64);                                   \
        }                                                                    \
        if (lane == 0) {                                                     \
            energies[(size_t)b0 * S + s_base + (kk)] = pa;                   \
            energies[(size_t)b1 * S + s_base + (kk)] = pb;                   \
        }                                                                    \
    }

__global__ __launch_bounds__(1024) void energies_kernel(
    const float* __restrict__ enc, const float* __restrict__ v,
    float* __restrict__ energies)
{
    const int w    = threadIdx.x >> 6;        // wave 0..15
    const int lane = threadIdx.x & 63;
    const int b0 = w, b1 = w + 16;
    const size_t base   = (size_t)blockIdx.x * 512;   // first row of block
    const int    s_base = blockIdx.x * 16;

    const float4* __restrict__ v4 = (const float4*)v;
    const float4 wa0 = v4[b0 * 256 + lane],       wa1 = v4[b0 * 256 + 64 + lane],
                 wa2 = v4[b0 * 256 + 128 + lane], wa3 = v4[b0 * 256 + 192 + lane];
    const float4 wb0 = v4[b1 * 256 + lane],       wb1 = v4[b1 * 256 + 64 + lane],
                 wb2 = v4[b1 * 256 + 128 + lane], wb3 = v4[b1 * 256 + 192 + lane];

    // rowA(k) = (base + w + 32k) * 256 float4;  rowB(k) = rowA(k) + 4096
    const float4* __restrict__ rbase = (const float4*)enc + (base + (size_t)w) * 256;

    float4 xa0, xa1, xa2, xa3, xb0, xb1, xb2, xb3;   // current
    float4 ya0, ya1, ya2, ya3, yb0, yb1, yb2, yb3;   // next

    { const float4* pA = rbase; const float4* pB = rbase + 4096;
      LOAD8(x, pA, pB) }

    #pragma unroll
    for (int k = 0; k < 16; k += 2) {
        { const float4* pA = rbase + (size_t)(k + 1) * 8192;
          const float4* pB = pA + 4096;
          LOAD8(y, pA, pB) }
        COMPUTE_STORE(x, k)
        if (k + 2 < 16) {
            const float4* pA = rbase + (size_t)(k + 2) * 8192;
            const float4* pB = pA + 4096;
            LOAD8(x, pA, pB)
        }
        COMPUTE_STORE(y, k + 1)
    }
}

// ---------------------------------------------------------------------------
// Kernel 3 v2: 32 blocks x 1024 thr, one float4 per thread, single pass.
// ---------------------------------------------------------------------------
__global__ __launch_bounds__(1024) void softmax_kernel(float* __restrict__ out)
{
    const int b = blockIdx.x;
    float4* __restrict__ row4 = (float4*)(out + (size_t)b * S);  // 1024 float4
    const int w = threadIdx.x >> 6;
    const int lane = threadIdx.x & 63;
    __shared__ float redm[16];
    __shared__ float reds[16];

    float4 x = row4[threadIdx.x];
    float m = fmaxf(fmaxf(x.x, x.y), fmaxf(x.z, x.w));
    #pragma unroll
    for (int off = 32; off > 0; off >>= 1)
        m = fmaxf(m, __shfl_xor(m, off, 64));
    if (lane == 0) redm[w] = m;
    __syncthreads();
    float M = redm[0];
    #pragma unroll
    for (int i = 1; i < 16; ++i) M = fmaxf(M, redm[i]);   // LDS broadcast reads

    float4 e;
    e.x = __expf(x.x - M); e.y = __expf(x.y - M);
    e.z = __expf(x.z - M); e.w = __expf(x.w - M);
    float s = (e.x + e.y) + (e.z + e.w);
    #pragma unroll
    for (int off = 32; off > 0; off >>= 1)
        s += __shfl_xor(s, off, 64);
    if (lane == 0) reds[w] = s;
    __syncthreads();
    float T = reds[0];
    #pragma unroll
    for (int i = 1; i < 16; ++i) T += reds[i];
    const float inv = 1.0f / T;
    e.x *= inv; e.y *= inv; e.z *= inv; e.w *= inv;
    row4[threadIdx.x] = e;
}

extern "C" void kernel_launch(void* const* d_in, const int* in_sizes, int n_in,
                              void* d_out, int out_size, void* d_ws, size_t ws_size,
                              hipStream_t stream) {
    const float* hidden = (const float*)d_in[0];   // [1, B, H]
    const float* enc    = (const float*)d_in[1];   // [S, B, H]
    const float* W      = (const float*)d_in[2];   // [H, H]
    // d_in[3] = attn_b: per-b constant in energies -> cancels under softmax.
    float* out = (float*)d_out;                    // [B, 1, S]
    float* v   = (float*)d_ws;                     // B*H floats

    compute_v_kernel<<<dim3(B * 16), dim3(256), 0, stream>>>(hidden, W, v);
    energies_kernel<<<dim3(256), dim3(1024), 0, stream>>>(enc, v, out);
    softmax_kernel<<<dim3(B), dim3(1024), 0, stream>>>(out);
}